// Round 3
// baseline (513.096 us; speedup 1.0000x reference)
//
#include <hip/hip_runtime.h>

// VQ: x [B=64, D=64, H=32, W=32] fp32, E [D=64, K=1024] fp32.
// flat rows N = B*H*W = 65536 over (b, h, w) order.
// d_out (float32): [0,4194304) quantized [B,D,H,W]; [4194304] dict_loss;
//   [4194305] commit_loss; [4194306,+65536) indices as floats.
//
// Structure: 1024 blocks x 64 rows. x-tile in LDS (16 KB, staged once).
// E read directly from L2 (256 KB, resident per-XCD): wave wv owns k-slice
// [kt*256 + wv*64, +64) per tile; lane = (rg=L>>3 -> 8 rows, kq=L&7 -> 8 k).
// acc[8][8] per thread; no barriers in the main loop; 4 blocks/CU co-resident.

#define DDIM 64
#define KNUM 1024
#define HWN  1024
#define ROWS_PER_BLOCK 64
#define KTILE 256
#define NKT (KNUM / KTILE)

__global__ __launch_bounds__(256) void vq_esq_kernel(const float* __restrict__ E,
                                                     float* __restrict__ esq) {
    int k = blockIdx.x * 256 + threadIdx.x;  // 4 blocks x 256 = 1024
    float s = 0.f;
    #pragma unroll 8
    for (int d = 0; d < DDIM; ++d) {
        float e = E[d * KNUM + k];
        s = fmaf(e, e, s);
    }
    esq[k] = s;
}

__global__ __launch_bounds__(256, 4) void vq_main_kernel(const float* __restrict__ x,
                                                         const float* __restrict__ E,
                                                         const float* __restrict__ esq,
                                                         float* __restrict__ out_q,
                                                         float* __restrict__ out_idx,
                                                         float* __restrict__ partial) {
    __shared__ float xlds[DDIM * ROWS_PER_BLOCK];  // [d][row] 16 KB
    __shared__ float bdls[4 * ROWS_PER_BLOCK];     // per-wave row winners (dist)
    __shared__ int   bkls[4 * ROWS_PER_BLOCK];     // per-wave row winners (k)
    __shared__ int   klds[ROWS_PER_BLOCK];
    __shared__ float redlds[4];

    const int t  = threadIdx.x;
    const int wv = t >> 6;        // wave 0..3: owns k-slice wv*64 per tile
    const int ln = t & 63;
    const int rg = ln >> 3;       // row group 0..7 -> rows rg*8 .. +7
    const int kq = ln & 7;        // k sub-lane -> k = k0 + wv*64 + kq*8 + m
    const int n0 = blockIdx.x * ROWS_PER_BLOCK;
    const int b   = n0 >> 10;
    const int hw0 = n0 & 1023;
    const float* xbase = x + (size_t)b * (DDIM * HWN) + hw0;

    // ---- stage x tile [64 d][64 rows] via global_load_lds (16B) ----
    #pragma unroll
    for (int it = 0; it < 4; ++it) {
        int dbase = it * 16 + wv * 4;
        int dsub  = ln >> 4;
        int off   = (ln & 15) * 4;
        const float* g = xbase + (dbase + dsub) * HWN + off;
        __builtin_amdgcn_global_load_lds(
            (const __attribute__((address_space(1))) void*)g,
            (__attribute__((address_space(3))) void*)&xlds[dbase * 64 + ln * 4],
            16, 0, 0);
    }
    __syncthreads();

    float best[8];
    int   bestk[8];
    #pragma unroll
    for (int r = 0; r < 8; ++r) { best[r] = 3.4e38f; bestk[r] = 0; }

    for (int kt = 0; kt < NKT; ++kt) {
        const int kbase = kt * KTILE + wv * 64 + kq * 8;
        const float4* ep = reinterpret_cast<const float4*>(E + kbase); // +d*256 per d

        float s[8][8];     // [row r][k m]
        #pragma unroll
        for (int r = 0; r < 8; ++r)
            #pragma unroll
            for (int m = 0; m < 8; ++m) s[r][m] = 0.f;

        float4 ca = ep[0], cb = ep[1];
        #pragma unroll 2
        for (int d = 0; d < DDIM - 1; ++d) {
            float4 na = ep[(d + 1) * (KNUM / 4)];
            float4 nb = ep[(d + 1) * (KNUM / 4) + 1];
            float4 xa = *reinterpret_cast<const float4*>(&xlds[d * 64 + rg * 8]);
            float4 xb = *reinterpret_cast<const float4*>(&xlds[d * 64 + rg * 8 + 4]);
            float xr[8] = {xa.x, xa.y, xa.z, xa.w, xb.x, xb.y, xb.z, xb.w};
            float ee[8] = {ca.x, ca.y, ca.z, ca.w, cb.x, cb.y, cb.z, cb.w};
            #pragma unroll
            for (int r = 0; r < 8; ++r)
                #pragma unroll
                for (int m = 0; m < 8; ++m)
                    s[r][m] = fmaf(xr[r], ee[m], s[r][m]);
            ca = na; cb = nb;
        }
        {   // d = 63
            const int d = DDIM - 1;
            float4 xa = *reinterpret_cast<const float4*>(&xlds[d * 64 + rg * 8]);
            float4 xb = *reinterpret_cast<const float4*>(&xlds[d * 64 + rg * 8 + 4]);
            float xr[8] = {xa.x, xa.y, xa.z, xa.w, xb.x, xb.y, xb.z, xb.w};
            float ee[8] = {ca.x, ca.y, ca.z, ca.w, cb.x, cb.y, cb.z, cb.w};
            #pragma unroll
            for (int r = 0; r < 8; ++r)
                #pragma unroll
                for (int m = 0; m < 8; ++m)
                    s[r][m] = fmaf(xr[r], ee[m], s[r][m]);
        }

        const float4* eqp = reinterpret_cast<const float4*>(esq + kbase);
        float4 eqa = eqp[0], eqb = eqp[1];
        float eq[8] = {eqa.x, eqa.y, eqa.z, eqa.w, eqb.x, eqb.y, eqb.z, eqb.w};
        #pragma unroll
        for (int m = 0; m < 8; ++m) {
            int k = kbase + m;
            #pragma unroll
            for (int r = 0; r < 8; ++r) {
                float dist = fmaf(-2.f, s[r][m], eq[m]);  // |e|^2 - 2 x.e
                if (dist < best[r] || (dist == best[r] && k < bestk[r])) {
                    best[r] = dist; bestk[r] = k;
                }
            }
        }
    }

    // reduce across the 8 kq-lanes of each row group (offsets 1,2,4)
    #pragma unroll
    for (int r = 0; r < 8; ++r) {
        float bd = best[r]; int bk = bestk[r];
        #pragma unroll
        for (int off = 4; off >= 1; off >>= 1) {
            float od = __shfl_xor(bd, off);
            int   ok = __shfl_xor(bk, off);
            if (od < bd || (od == bd && ok < bk)) { bd = od; bk = ok; }
        }
        if (kq == 0) { bdls[wv * 64 + rg * 8 + r] = bd; bkls[wv * 64 + rg * 8 + r] = bk; }
    }
    __syncthreads();

    // cross-wave merge: thread t<64 owns row t
    if (t < ROWS_PER_BLOCK) {
        float bd = bdls[t]; int bk = bkls[t];
        #pragma unroll
        for (int w = 1; w < 4; ++w) {
            float od = bdls[w * 64 + t]; int ok = bkls[w * 64 + t];
            if (od < bd || (od == bd && ok < bk)) { bd = od; bk = ok; }
        }
        klds[t] = bk;
        out_idx[n0 + t] = (float)bk;
    }
    __syncthreads();

    // epilogue: gather E columns, write quantized coalesced, loss partial
    float lsum = 0.f;
    float* outbase = out_q + (size_t)b * (DDIM * HWN) + hw0;
    #pragma unroll 4
    for (int it = 0; it < 16; ++it) {
        int d = it * 4 + (t >> 6);
        int r = t & 63;
        int k = klds[r];
        float q  = E[d * KNUM + k];
        float xv = xlds[d * 64 + r];
        float diff = xv - q;
        lsum = fmaf(diff, diff, lsum);
        outbase[d * HWN + r] = q;
    }

    #pragma unroll
    for (int off = 32; off >= 1; off >>= 1)
        lsum += __shfl_xor(lsum, off);
    if ((t & 63) == 0) redlds[t >> 6] = lsum;
    __syncthreads();
    if (t == 0)
        partial[blockIdx.x] = (redlds[0] + redlds[1]) + (redlds[2] + redlds[3]);
}

__global__ __launch_bounds__(256) void vq_loss_kernel(const float* __restrict__ partial,
                                                      float* __restrict__ out_loss) {
    __shared__ float red[4];
    int t = threadIdx.x;
    float s = 0.f;
    #pragma unroll
    for (int it = 0; it < 4; ++it) s += partial[it * 256 + t];
    #pragma unroll
    for (int off = 32; off >= 1; off >>= 1) s += __shfl_xor(s, off);
    if ((t & 63) == 0) red[t >> 6] = s;
    __syncthreads();
    if (t == 0) {
        float loss = ((red[0] + red[1]) + (red[2] + red[3])) / 4194304.f;
        out_loss[0] = loss;   // dictionary_loss
        out_loss[1] = loss;   // commitment_loss (numerically identical)
    }
}

extern "C" void kernel_launch(void* const* d_in, const int* in_sizes, int n_in,
                              void* d_out, int out_size, void* d_ws, size_t ws_size,
                              hipStream_t stream) {
    const float* x = (const float*)d_in[0];
    const float* E = (const float*)d_in[1];
    float* out      = (float*)d_out;
    float* out_q    = out;             // 4194304
    float* out_loss = out + 4194304;   // 2 scalars
    float* out_idx  = out + 4194306;   // 65536 indices (as float)
    float* esq      = (float*)d_ws;    // 1024 floats
    float* partial  = esq + 1024;      // 1024 floats

    vq_esq_kernel<<<4, 256, 0, stream>>>(E, esq);
    vq_main_kernel<<<1024, 256, 0, stream>>>(x, E, esq, out_q, out_idx, partial);
    vq_loss_kernel<<<1, 256, 0, stream>>>(partial, out_loss);
}

// Round 4
// 138.147 us; speedup vs baseline: 3.7141x; 3.7141x over previous
//
#include <hip/hip_runtime.h>

// VQ: x [B=64, D=64, H=32, W=32] fp32, E [D=64, K=1024] fp32.
// flat rows N = B*H*W = 65536 over (b, h, w) order.
// d_out (float32): [0,4194304) quantized [B,D,H,W]; [4194304] dict_loss;
//   [4194305] commit_loss; [4194306,+65536) indices as floats.
//
// Round-2 structure (proven 135us) + XOR-swizzled E LDS layout:
//   - E staged via global_load_lds with LINEAR dest + pre-swizzled global src
//     (granule g = ln ^ ((ln>>3)&7), involution), read back with the same
//     permutation -> e-reads spread over all 8 bank-quads (was 8-way conflict).
//   - esq in registers (global L2 read), not LDS.
//   - launch_bounds(256,2): VGPR cap 256 -> NO accumulator spill (round-3 bug).

#define DDIM 64
#define KNUM 1024
#define HWN  1024
#define ROWS_PER_BLOCK 64
#define KTILE 256
#define NKT (KNUM / KTILE)

__global__ __launch_bounds__(256) void vq_esq_kernel(const float* __restrict__ E,
                                                     float* __restrict__ esq) {
    int k = blockIdx.x * 256 + threadIdx.x;  // 4 blocks x 256 = 1024
    float s = 0.f;
    #pragma unroll 8
    for (int d = 0; d < DDIM; ++d) {
        float e = E[d * KNUM + k];
        s = fmaf(e, e, s);
    }
    esq[k] = s;
}

__global__ __launch_bounds__(256, 2) void vq_main_kernel(const float* __restrict__ x,
                                                         const float* __restrict__ E,
                                                         const float* __restrict__ esq,
                                                         float* __restrict__ out_q,
                                                         float* __restrict__ out_idx,
                                                         float* __restrict__ partial) {
    __shared__ float xlds[DDIM * ROWS_PER_BLOCK];  // [d][row] 16 KB
    __shared__ float elds[DDIM * KTILE];           // [d][64 granules swizzled] 64 KB

    const int t  = threadIdx.x;
    const int kl = t & 31;   // k-lane: owns k = k0 + kl*8 + m
    const int rg = t >> 5;   // row-group: owns rows rg*8 .. rg*8+7
    const int wv = t >> 6;   // wave id 0..3
    const int ln = t & 63;   // lane id
    const int n0 = blockIdx.x * ROWS_PER_BLOCK;
    const int b   = n0 >> 10;
    const int hw0 = n0 & 1023;
    const float* xbase = x + (size_t)b * (DDIM * HWN) + hw0;

    // swizzle maps (16B granules within a 64-granule row): involution s = g ^ ((g>>3)&7)
    const int gsrc = ln ^ ((ln >> 3) & 7);          // global source granule for linear dest ln
    const int sa   = (2 * kl) ^ ((kl >> 2) & 7);    // LDS slot of original granule 2*kl
    const int sb   = sa ^ 1;                        // LDS slot of original granule 2*kl+1

    // ---- stage x tile [64 d][64 rows] via global_load_lds (16B), linear ----
    #pragma unroll
    for (int it = 0; it < 4; ++it) {
        int dbase = it * 16 + wv * 4;
        int dsub  = ln >> 4;
        int off   = (ln & 15) * 4;
        const float* g = xbase + (dbase + dsub) * HWN + off;
        __builtin_amdgcn_global_load_lds(
            (const __attribute__((address_space(1))) void*)g,
            (__attribute__((address_space(3))) void*)&xlds[dbase * 64 + ln * 4],
            16, 0, 0);
    }

    float best[8];
    int   bestk[8];
    #pragma unroll
    for (int r = 0; r < 8; ++r) { best[r] = 3.4e38f; bestk[r] = 0; }

    for (int kt = 0; kt < NKT; ++kt) {
        const int k0 = kt * KTILE;
        __syncthreads();   // previous tile's readers done (kt=0: no-op)
        // ---- stage E tile [64 d][256 k]: linear LDS dest, swizzled global src ----
        #pragma unroll
        for (int it = 0; it < 16; ++it) {
            int d = it * 4 + wv;
            const float* g = E + d * KNUM + k0 + gsrc * 4;
            __builtin_amdgcn_global_load_lds(
                (const __attribute__((address_space(1))) void*)g,
                (__attribute__((address_space(3))) void*)&elds[d * KTILE + ln * 4],
                16, 0, 0);
        }
        // |e_k|^2 for my 8 k's -> regs (L2-hot)
        float4 eqa = *reinterpret_cast<const float4*>(esq + k0 + kl * 8);
        float4 eqb = *reinterpret_cast<const float4*>(esq + k0 + kl * 8 + 4);
        __syncthreads();   // barrier drains vmcnt -> staged data visible

        float s[8][8];     // [row r][k m]
        #pragma unroll
        for (int r = 0; r < 8; ++r)
            #pragma unroll
            for (int m = 0; m < 8; ++m) s[r][m] = 0.f;

        #pragma unroll 4
        for (int d = 0; d < DDIM; ++d) {
            float4 xa = *reinterpret_cast<const float4*>(&xlds[d * 64 + rg * 8]);
            float4 xb = *reinterpret_cast<const float4*>(&xlds[d * 64 + rg * 8 + 4]);
            float4 ea = *reinterpret_cast<const float4*>(&elds[d * KTILE + sa * 4]);
            float4 eb = *reinterpret_cast<const float4*>(&elds[d * KTILE + sb * 4]);
            float xr[8] = {xa.x, xa.y, xa.z, xa.w, xb.x, xb.y, xb.z, xb.w};
            float ee[8] = {ea.x, ea.y, ea.z, ea.w, eb.x, eb.y, eb.z, eb.w};
            #pragma unroll
            for (int r = 0; r < 8; ++r)
                #pragma unroll
                for (int m = 0; m < 8; ++m)
                    s[r][m] = fmaf(xr[r], ee[m], s[r][m]);
        }

        float eq[8] = {eqa.x, eqa.y, eqa.z, eqa.w, eqb.x, eqb.y, eqb.z, eqb.w};
        #pragma unroll
        for (int m = 0; m < 8; ++m) {
            int k = k0 + kl * 8 + m;
            #pragma unroll
            for (int r = 0; r < 8; ++r) {
                float dist = fmaf(-2.f, s[r][m], eq[m]);  // |e|^2 - 2 x.e
                if (dist < best[r] || (dist == best[r] && k < bestk[r])) {
                    best[r] = dist; bestk[r] = k;
                }
            }
        }
    }

    __syncthreads();   // all compute done; elds now dead -> alias klds/redlds
    int*   klds   = (int*)elds;
    float* redlds = elds + 64;

    // argmin reduce across the 32 k-lanes of each half-wave
    #pragma unroll
    for (int r = 0; r < 8; ++r) {
        float bd = best[r]; int bk = bestk[r];
        #pragma unroll
        for (int off = 16; off >= 1; off >>= 1) {
            float od = __shfl_xor(bd, off, 32);
            int   ok = __shfl_xor(bk, off, 32);
            if (od < bd || (od == bd && ok < bk)) { bd = od; bk = ok; }
        }
        if (kl == 0) klds[rg * 8 + r] = bk;
    }
    __syncthreads();

    if (t < ROWS_PER_BLOCK) {
        out_idx[n0 + t] = (float)klds[t];
    }

    // epilogue: gather E columns, write quantized coalesced, loss partial
    float lsum = 0.f;
    float* outbase = out_q + (size_t)b * (DDIM * HWN) + hw0;
    #pragma unroll 4
    for (int it = 0; it < 16; ++it) {
        int d = it * 4 + (t >> 6);
        int r = t & 63;
        int k = klds[r];
        float q  = E[d * KNUM + k];
        float xv = xlds[d * 64 + r];
        float diff = xv - q;
        lsum = fmaf(diff, diff, lsum);
        outbase[d * HWN + r] = q;
    }

    #pragma unroll
    for (int off = 32; off >= 1; off >>= 1)
        lsum += __shfl_xor(lsum, off);
    if ((t & 63) == 0) redlds[t >> 6] = lsum;
    __syncthreads();
    if (t == 0)
        partial[blockIdx.x] = (redlds[0] + redlds[1]) + (redlds[2] + redlds[3]);
}

__global__ __launch_bounds__(256) void vq_loss_kernel(const float* __restrict__ partial,
                                                      float* __restrict__ out_loss) {
    __shared__ float red[4];
    int t = threadIdx.x;
    float s = 0.f;
    #pragma unroll
    for (int it = 0; it < 4; ++it) s += partial[it * 256 + t];
    #pragma unroll
    for (int off = 32; off >= 1; off >>= 1) s += __shfl_xor(s, off);
    if ((t & 63) == 0) red[t >> 6] = s;
    __syncthreads();
    if (t == 0) {
        float loss = ((red[0] + red[1]) + (red[2] + red[3])) / 4194304.f;
        out_loss[0] = loss;   // dictionary_loss
        out_loss[1] = loss;   // commitment_loss (numerically identical)
    }
}

extern "C" void kernel_launch(void* const* d_in, const int* in_sizes, int n_in,
                              void* d_out, int out_size, void* d_ws, size_t ws_size,
                              hipStream_t stream) {
    const float* x = (const float*)d_in[0];
    const float* E = (const float*)d_in[1];
    float* out      = (float*)d_out;
    float* out_q    = out;             // 4194304
    float* out_loss = out + 4194304;   // 2 scalars
    float* out_idx  = out + 4194306;   // 65536 indices (as float)
    float* esq      = (float*)d_ws;    // 1024 floats
    float* partial  = esq + 1024;      // 1024 floats

    vq_esq_kernel<<<4, 256, 0, stream>>>(E, esq);
    vq_main_kernel<<<1024, 256, 0, stream>>>(x, E, esq, out_q, out_idx, partial);
    vq_loss_kernel<<<1, 256, 0, stream>>>(partial, out_loss);
}

// Round 5
// 130.659 us; speedup vs baseline: 3.9270x; 1.0573x over previous
//
#include <hip/hip_runtime.h>

// VQ: x [B=64, D=64, H=32, W=32] fp32, E [D=64, K=1024] fp32.
// flat rows N = B*H*W = 65536 over (b, h, w) order.
// d_out (float32): [0,4194304) quantized [B,D,H,W]; [4194304] dict_loss;
//   [4194305] commit_loss; [4194306,+65536) indices as floats.
//
// Round-5 structure: lane = row, wave = 8-k slice.
//   x: LDS [d][row], read as stride-1 b32 (2-way alias = free broadcast).
//   E: wave-uniform 32B loads straight from L2 (256 KB resident) - no LDS.
//   No barriers / no shuffles in the main loop; acc = 8 regs per thread.

#define DDIM 64
#define KNUM 1024
#define HWN  1024
#define ROWS_PER_BLOCK 64

typedef __attribute__((ext_vector_type(8))) float float8v;

__global__ __launch_bounds__(256) void vq_esq_kernel(const float* __restrict__ E,
                                                     float* __restrict__ esq) {
    int k = blockIdx.x * 256 + threadIdx.x;  // 4 blocks x 256 = 1024
    float s = 0.f;
    #pragma unroll 8
    for (int d = 0; d < DDIM; ++d) {
        float e = E[d * KNUM + k];
        s = fmaf(e, e, s);
    }
    esq[k] = s;
}

__global__ __launch_bounds__(256, 4) void vq_main_kernel(const float* __restrict__ x,
                                                         const float* __restrict__ E,
                                                         const float* __restrict__ esq,
                                                         float* __restrict__ out_q,
                                                         float* __restrict__ out_idx,
                                                         float* __restrict__ partial) {
    __shared__ float xlds[DDIM * ROWS_PER_BLOCK];  // [d][row] 16 KB
    __shared__ float bdls[4 * ROWS_PER_BLOCK];     // per-wave row winners (dist)
    __shared__ int   bkls[4 * ROWS_PER_BLOCK];     // per-wave row winners (k)
    __shared__ int   klds[ROWS_PER_BLOCK];
    __shared__ float redlds[4];

    const int t  = threadIdx.x;
    const int wv = t >> 6;        // wave 0..3
    const int ln = t & 63;        // lane = row
    const int n0 = blockIdx.x * ROWS_PER_BLOCK;
    const int b   = n0 >> 10;
    const int hw0 = n0 & 1023;
    const float* xbase = x + (size_t)b * (DDIM * HWN) + hw0;

    // ---- stage x tile [64 d][64 rows] via global_load_lds (16B), linear ----
    #pragma unroll
    for (int it = 0; it < 4; ++it) {
        int dbase = it * 16 + wv * 4;
        int dsub  = ln >> 4;
        int off   = (ln & 15) * 4;
        const float* g = xbase + (dbase + dsub) * HWN + off;
        __builtin_amdgcn_global_load_lds(
            (const __attribute__((address_space(1))) void*)g,
            (__attribute__((address_space(3))) void*)&xlds[dbase * 64 + ln * 4],
            16, 0, 0);
    }
    __syncthreads();

    const int wvu = __builtin_amdgcn_readfirstlane(wv);  // wave-uniform

    float best  = 3.4e38f;
    int   bestk = 0;

    // 32 k-iters; wave wv covers k = kt*32 + wvu*8 .. +7 each iter.
    for (int kt = 0; kt < 32; ++kt) {
        const int kbase = kt * 32 + wvu * 8;
        const float* ep = E + kbase;

        float s[8];
        #pragma unroll
        for (int m = 0; m < 8; ++m) s[m] = 0.f;

        #pragma unroll 8
        for (int d = 0; d < DDIM; ++d) {
            float   xv = xlds[d * 64 + ln];                       // stride-1 b32
            float8v ee = *reinterpret_cast<const float8v*>(ep + d * KNUM);  // uniform 32B
            #pragma unroll
            for (int m = 0; m < 8; ++m)
                s[m] = fmaf(xv, ee[m], s[m]);
        }

        float8v eq = *reinterpret_cast<const float8v*>(esq + kbase);
        #pragma unroll
        for (int m = 0; m < 8; ++m) {
            float dist = fmaf(-2.f, s[m], eq[m]);   // |e|^2 - 2 x.e  (|x|^2 const per row)
            int   k    = kbase + m;
            if (dist < best) { best = dist; bestk = k; }   // m,kt ascending -> first-min
        }
    }

    bdls[wv * 64 + ln] = best;
    bkls[wv * 64 + ln] = bestk;
    __syncthreads();

    // cross-wave merge: thread t<64 owns row t (lexicographic (dist, k) min)
    if (t < ROWS_PER_BLOCK) {
        float bd = bdls[t]; int bk = bkls[t];
        #pragma unroll
        for (int w = 1; w < 4; ++w) {
            float od = bdls[w * 64 + t]; int ok = bkls[w * 64 + t];
            if (od < bd || (od == bd && ok < bk)) { bd = od; bk = ok; }
        }
        klds[t] = bk;
        out_idx[n0 + t] = (float)bk;
    }
    __syncthreads();

    // epilogue: gather E columns, write quantized coalesced, loss partial
    float lsum = 0.f;
    float* outbase = out_q + (size_t)b * (DDIM * HWN) + hw0;
    #pragma unroll 4
    for (int it = 0; it < 16; ++it) {
        int d = it * 4 + (t >> 6);
        int r = t & 63;
        int k = klds[r];
        float q  = E[d * KNUM + k];
        float xv = xlds[d * 64 + r];
        float diff = xv - q;
        lsum = fmaf(diff, diff, lsum);
        outbase[d * HWN + r] = q;
    }

    #pragma unroll
    for (int off = 32; off >= 1; off >>= 1)
        lsum += __shfl_xor(lsum, off);
    if ((t & 63) == 0) redlds[t >> 6] = lsum;
    __syncthreads();
    if (t == 0)
        partial[blockIdx.x] = (redlds[0] + redlds[1]) + (redlds[2] + redlds[3]);
}

__global__ __launch_bounds__(256) void vq_loss_kernel(const float* __restrict__ partial,
                                                      float* __restrict__ out_loss) {
    __shared__ float red[4];
    int t = threadIdx.x;
    float s = 0.f;
    #pragma unroll
    for (int it = 0; it < 4; ++it) s += partial[it * 256 + t];
    #pragma unroll
    for (int off = 32; off >= 1; off >>= 1) s += __shfl_xor(s, off);
    if ((t & 63) == 0) red[t >> 6] = s;
    __syncthreads();
    if (t == 0) {
        float loss = ((red[0] + red[1]) + (red[2] + red[3])) / 4194304.f;
        out_loss[0] = loss;   // dictionary_loss
        out_loss[1] = loss;   // commitment_loss (numerically identical)
    }
}

extern "C" void kernel_launch(void* const* d_in, const int* in_sizes, int n_in,
                              void* d_out, int out_size, void* d_ws, size_t ws_size,
                              hipStream_t stream) {
    const float* x = (const float*)d_in[0];
    const float* E = (const float*)d_in[1];
    float* out      = (float*)d_out;
    float* out_q    = out;             // 4194304
    float* out_loss = out + 4194304;   // 2 scalars
    float* out_idx  = out + 4194306;   // 65536 indices (as float)
    float* esq      = (float*)d_ws;    // 1024 floats
    float* partial  = esq + 1024;      // 1024 floats

    vq_esq_kernel<<<4, 256, 0, stream>>>(E, esq);
    vq_main_kernel<<<1024, 256, 0, stream>>>(x, E, esq, out_q, out_idx, partial);
    vq_loss_kernel<<<1, 256, 0, stream>>>(partial, out_loss);
}